// Round 11
// baseline (297.643 us; speedup 1.0000x reference)
//
#include <hip/hip_runtime.h>
#include <math.h>

#define DIM 128
// ws float layout:
//   G^(2^s)  s=0..5 : GP(s)        GT^(2^s) : GTP(s)
//   Y'[j] (64x128 batch-major) j=0..63 : YP(j)
//   Xa^q q=1..8 : XOFF(q)          XaT^q : XTOFF(q)
//   T_i i=1..64 : TOFF(i)
//   Wf f16 frags : FWOFFI (64 x 16384 halves)   Yf f16 frags : FYOFFI (64 x 8192 halves)
#define GP(s)    ((s) * 16384)
#define GTP(s)   ((6 + (s)) * 16384)
#define YP(j)    (13 * 16384 + (j) * 8192)
#define XOFF(q)  ((44 + (q)) * 16384)
#define XTOFF(q) ((52 + (q)) * 16384)
#define TOFF(i)  ((60 + (i)) * 16384)
#define FWOFFI   (125 * 16384)
#define FYOFFI   (157 * 16384)
#define ALPHA    16.0f

typedef _Float16 f16x8 __attribute__((ext_vector_type(8)));
typedef float    f32x4 __attribute__((ext_vector_type(4)));

__device__ __forceinline__ float4 ld4(const float* p) { return *(const float4*)p; }

__device__ __forceinline__ void splitv(const float* src, f16x8& h8, f16x8& l8)
{
    float4 p = ld4(src), r = ld4(src + 4);
    float v[8] = {p.x, p.y, p.z, p.w, r.x, r.y, r.z, r.w};
    #pragma unroll
    for (int q = 0; q < 8; q++) {
        _Float16 h = (_Float16)v[q];
        h8[q] = h; l8[q] = (_Float16)(v[q] - (float)h);
    }
}

__device__ __forceinline__ void stageA(const float* __restrict__ A, float* AT, int tid)
{
    for (int idx = tid; idx < DIM * DIM; idx += 256)
        AT[(idx & 127) * 132 + (idx >> 7)] = A[idx];
}

__device__ __forceinline__ void mm_core(const float* AT, const float* Bs,
                                        float (&acc)[4][4], int tid)
{
    int d0 = (tid & 31) * 4, c0 = (tid >> 5) * 4;
    #pragma unroll 4
    for (int k = 0; k < DIM; k++) {
        float4 a4 = ld4(&AT[k * 132 + d0]);
        float4 b4 = ld4(&Bs[k * 36 + c0]);
        float a_[4] = {a4.x, a4.y, a4.z, a4.w};
        float b_[4] = {b4.x, b4.y, b4.z, b4.w};
        #pragma unroll
        for (int i = 0; i < 4; i++)
            #pragma unroll
            for (int j = 0; j < 4; j++) acc[i][j] += a_[i] * b_[j];
    }
}

// ---- L1: Xa + XaT (f32), Xa^2 + Xa^2T; Y'0 (batch-major) + Yf0 + Wf0 ------
__global__ __launch_bounds__(256) void k_x2(const float* __restrict__ t,
                                            const float* __restrict__ x0,
                                            const float* __restrict__ S,
                                            const float* __restrict__ D,
                                            float* __restrict__ ws)
{
    __shared__ __align__(16) float AT[DIM * 132];
    __shared__ __align__(16) float Bs[DIM * 36];
    int tid = threadIdx.x, bid = blockIdx.x, cpan = bid * 32;
    float sc = (t[1] - t[0]) * ALPHA;
    for (int e = tid; e < 16384; e += 256) {
        int r = e >> 7, c = e & 127;
        float a;
        if (r == c)      a = -log1pf(expf(D[r]));
        else if (r < c)  a =  S[(r * (2 * DIM - r - 1)) / 2 + (c - r - 1)];
        else             a = -S[(c * (2 * DIM - c - 1)) / 2 + (r - c - 1)];
        a *= sc;
        AT[c * 132 + r] = a;
        if (c >= cpan && c < cpan + 32) Bs[r * 36 + (c - cpan)] = a;
        if (bid == 0) { ws[XOFF(1) + e] = a; ws[XTOFF(1) + c * DIM + r] = a; }
    }
    if (bid == 1) {                                  // Y'0 batch-major + Yf0 frags
        for (int e = tid; e < 8192; e += 256) {
            int b = e >> 7, d = e & 127;
            ws[YP(0) + e] = x0[(size_t)d * 64 + b];
        }
        _Float16* Yf = (_Float16*)(ws + FYOFFI);
        for (int slot = tid; slot < 1024; slot += 256) {
            int ls = slot & 63, tile = slot >> 6;
            int n = (tile >> 2) * 16 + (ls & 15);
            int k0 = (tile & 3) * 32 + ((ls >> 4) & 3) * 8;
            f16x8 hv;
            #pragma unroll
            for (int q = 0; q < 8; q++) hv[q] = (_Float16)x0[(size_t)(k0 + q) * 64 + n];
            *(f16x8*)(Yf + (size_t)slot * 8) = hv;
        }
    }
    if (bid == 2) {                                  // W0 = I fragment table
        _Float16* Wf = (_Float16*)(ws + FWOFFI);
        for (int ch = tid; ch < 2048; ch += 256) {
            int m = ch >> 4, k0 = (ch & 15) << 3;
            f16x8 hv;
            #pragma unroll
            for (int q = 0; q < 8; q++) hv[q] = (m == k0 + q) ? (_Float16)1.0f : (_Float16)0.0f;
            int lane = (m & 15) | (((k0 >> 3) & 3) << 4);
            size_t off = (((size_t)(m >> 4) * 4 + (k0 >> 5)) * 64 + lane) * 8;
            *(f16x8*)(Wf + off) = hv;
        }
    }
    __syncthreads();
    float acc[4][4] = {};
    mm_core(AT, Bs, acc, tid);
    int d0 = (tid & 31) * 4, c0 = (tid >> 5) * 4;
    #pragma unroll
    for (int r = 0; r < 4; r++) {
        float4 st = make_float4(acc[r][0], acc[r][1], acc[r][2], acc[r][3]);
        *(float4*)&ws[XOFF(2) + (size_t)(d0 + r) * DIM + cpan + c0] = st;
        #pragma unroll
        for (int j = 0; j < 4; j++)
            ws[XTOFF(2) + (size_t)(cpan + c0 + j) * DIM + d0 + r] = acc[r][j];
    }
}

// ---- MFMA hi/lo atom (coalesced frag loads from A rows + Bt rows) ---------
// type 0: C(128x128) = A @ Bt^T, emit C and C^T (aux = CT offset)
// type 1: C(64x128)  = A @ Bt^T, emit C f32 + Yf A-frag table (aux = frag j)
struct AJobs { int4 a[32]; int aux[32]; };

__global__ __launch_bounds__(256) void k_atom(float* __restrict__ ws, AJobs JB)
{
    __shared__ __align__(16) float Cst[DIM * 133];   // 68 KB
    const int tid = threadIdx.x, wave = tid >> 6, lane = tid & 63;
    const int4 jb = JB.a[blockIdx.x];
    const int aux = JB.aux[blockIdx.x];
    const int type = jb.w;
    const float* A  = ws + jb.x;
    const float* Bt = ws + jb.y;
    float* C        = ws + jb.z;
    const int nmt = (type == 0) ? 2 : 1;
    const int mlane = lane & 15, koct = (lane >> 4) & 3;

    f16x8 ah[2][4], al[2][4];
    #pragma unroll
    for (int mt = 0; mt < 2; mt++) {
        if (mt >= nmt) break;
        #pragma unroll
        for (int kc = 0; kc < 4; kc++) {
            int m = (wave * nmt + mt) * 16 + mlane;
            splitv(A + (size_t)m * DIM + kc * 32 + koct * 8, ah[mt][kc], al[mt][kc]);
        }
    }
    f32x4 acc[2][8] = {};
    for (int kc = 0; kc < 4; kc++) {
        #pragma unroll
        for (int nt = 0; nt < 8; nt++) {
            int n = nt * 16 + mlane;
            f16x8 bh, bl;
            splitv(Bt + (size_t)n * DIM + kc * 32 + koct * 8, bh, bl);
            #pragma unroll
            for (int mt = 0; mt < 2; mt++) {
                if (mt >= nmt) break;
                acc[mt][nt] = __builtin_amdgcn_mfma_f32_16x16x32_f16(ah[mt][kc], bh, acc[mt][nt], 0, 0, 0);
                acc[mt][nt] = __builtin_amdgcn_mfma_f32_16x16x32_f16(ah[mt][kc], bl, acc[mt][nt], 0, 0, 0);
                acc[mt][nt] = __builtin_amdgcn_mfma_f32_16x16x32_f16(al[mt][kc], bh, acc[mt][nt], 0, 0, 0);
            }
        }
    }
    #pragma unroll
    for (int mt = 0; mt < 2; mt++) {
        if (mt >= nmt) break;
        #pragma unroll
        for (int nt = 0; nt < 8; nt++) {
            int row = (wave * nmt + mt) * 16 + (lane >> 4) * 4;
            int col = nt * 16 + mlane;
            #pragma unroll
            for (int p = 0; p < 4; p++) Cst[(size_t)(row + p) * 133 + col] = acc[mt][nt][p];
        }
    }
    __syncthreads();
    const int M = nmt * 64;
    for (int e = tid * 4; e < M * DIM; e += 1024) {
        int row = e >> 7, col = e & 127;
        const float* s = &Cst[(size_t)row * 133 + col];
        *(float4*)&C[e] = make_float4(s[0], s[1], s[2], s[3]);
    }
    if (type == 0) {
        float* Ct = ws + aux;
        for (int e = tid * 4; e < 16384; e += 1024) {
            int crow = e >> 7, r0 = e & 127;
            *(float4*)&Ct[e] = make_float4(Cst[(size_t)(r0 + 0) * 133 + crow],
                                           Cst[(size_t)(r0 + 1) * 133 + crow],
                                           Cst[(size_t)(r0 + 2) * 133 + crow],
                                           Cst[(size_t)(r0 + 3) * 133 + crow]);
        }
    } else {
        _Float16* Yf = (_Float16*)(ws + FYOFFI) + (size_t)aux * 8192;
        for (int slot = tid; slot < 1024; slot += 256) {
            int ls = slot & 63, tile = slot >> 6;
            int m = (tile >> 2) * 16 + (ls & 15);
            int k0 = (tile & 3) * 32 + ((ls >> 4) & 3) * 8;
            f16x8 hv;
            #pragma unroll
            for (int q = 0; q < 8; q++) hv[q] = (_Float16)Cst[(size_t)m * 133 + k0 + q];
            *(f16x8*)(Yf + (size_t)slot * 8) = hv;
        }
    }
}

// ---- L4: T_i = Xa8 @ P2(i) + P1(i), i=1..64 (f32, grid 64x4) --------------
__global__ __launch_bounds__(256) void k_ps1(float* __restrict__ ws)
{
    __shared__ __align__(16) float AT[DIM * 132];
    __shared__ __align__(16) float Bs[DIM * 36];
    int i = blockIdx.x + 1, cpan = blockIdx.y * 32, tid = threadIdx.x;
    float r = (float)i / ALPHA;
    float c[24]; c[0] = 1.0f;
    #pragma unroll
    for (int n = 1; n < 24; n++) c[n] = c[n - 1] * (r / (float)n);
    stageA(ws + XOFF(8), AT, tid);
    for (int idx = tid; idx < DIM * 8; idx += 256) {
        int k = idx >> 3, cc4 = (idx & 7) * 4;
        float4 b = make_float4(0.f, 0.f, 0.f, 0.f);
        #pragma unroll
        for (int q = 1; q < 8; q++) {
            float4 x = ld4(&ws[XOFF(q) + (size_t)k * DIM + cpan + cc4]);
            b.x += c[16 + q] * x.x; b.y += c[16 + q] * x.y;
            b.z += c[16 + q] * x.z; b.w += c[16 + q] * x.w;
        }
        int col = cpan + cc4;
        if (k >= col && k < col + 4) (&b.x)[k - col] += c[16];
        *(float4*)&Bs[k * 36 + cc4] = b;
    }
    __syncthreads();
    float acc[4][4] = {};
    mm_core(AT, Bs, acc, tid);
    int d0 = (tid & 31) * 4, c0 = (tid >> 5) * 4;
    float* T = ws + TOFF(i);
    #pragma unroll
    for (int rr = 0; rr < 4; rr++) {
        int dd = d0 + rr;
        float add[4] = {0.f, 0.f, 0.f, 0.f};
        #pragma unroll
        for (int q = 1; q < 8; q++) {
            float4 x = ld4(&ws[XOFF(q) + (size_t)dd * DIM + cpan + c0]);
            add[0] += c[8 + q] * x.x; add[1] += c[8 + q] * x.y;
            add[2] += c[8 + q] * x.z; add[3] += c[8 + q] * x.w;
        }
        int col0 = cpan + c0;
        if (dd >= col0 && dd < col0 + 4) add[dd - col0] += c[8];
        float4 st = make_float4(acc[rr][0] + add[0], acc[rr][1] + add[1],
                                acc[rr][2] + add[2], acc[rr][3] + add[3]);
        *(float4*)&T[(size_t)dd * DIM + cpan + c0] = st;
    }
}

// ---- L5: E^i = Xa8 @ T_i + P0(i); i<64 -> Wf frags, i=64 -> G0 + GT0 ------
__global__ __launch_bounds__(256) void k_ps2(float* __restrict__ ws)
{
    __shared__ __align__(16) float AT[DIM * 132];
    __shared__ __align__(16) float Bs[DIM * 36];
    int i = blockIdx.x + 1, cpan = blockIdx.y * 32, tid = threadIdx.x;
    float r = (float)i / ALPHA;
    float c[8]; c[0] = 1.0f;
    #pragma unroll
    for (int n = 1; n < 8; n++) c[n] = c[n - 1] * (r / (float)n);
    stageA(ws + XOFF(8), AT, tid);
    const float* T = ws + TOFF(i);
    for (int idx = tid; idx < DIM * 32; idx += 256) {
        int k = idx >> 5, cc = idx & 31;
        Bs[k * 36 + cc] = T[(size_t)k * DIM + cpan + cc];
    }
    __syncthreads();
    float acc[4][4] = {};
    mm_core(AT, Bs, acc, tid);
    int d0 = (tid & 31) * 4, c0 = (tid >> 5) * 4;
    #pragma unroll
    for (int rr = 0; rr < 4; rr++) {
        int dd = d0 + rr;
        float add[4] = {0.f, 0.f, 0.f, 0.f};
        #pragma unroll
        for (int q = 1; q < 8; q++) {
            float4 x = ld4(&ws[XOFF(q) + (size_t)dd * DIM + cpan + c0]);
            add[0] += c[q] * x.x; add[1] += c[q] * x.y;
            add[2] += c[q] * x.z; add[3] += c[q] * x.w;
        }
        int col0 = cpan + c0;
        if (dd >= col0 && dd < col0 + 4) add[dd - col0] += 1.0f;
        #pragma unroll
        for (int j = 0; j < 4; j++) acc[rr][j] += add[j];
    }
    if (i == 64) {
        #pragma unroll
        for (int rr = 0; rr < 4; rr++) {
            int dd = d0 + rr;
            float4 st = make_float4(acc[rr][0], acc[rr][1], acc[rr][2], acc[rr][3]);
            *(float4*)&ws[GP(0) + (size_t)dd * DIM + cpan + c0] = st;
            #pragma unroll
            for (int j = 0; j < 4; j++)
                ws[GTP(0) + (size_t)(cpan + c0 + j) * DIM + dd] = acc[rr][j];
        }
        return;
    }
    __syncthreads();
    #pragma unroll
    for (int rr = 0; rr < 4; rr++)
        #pragma unroll
        for (int j = 0; j < 4; j++) Bs[(d0 + rr) * 36 + c0 + j] = acc[rr][j];
    __syncthreads();
    _Float16* Wf = (_Float16*)(ws + FWOFFI);
    for (int ch = tid; ch < 512; ch += 256) {
        int m = ch >> 2, k0l = (ch & 3) * 8, k0 = cpan + k0l;
        f16x8 hv;
        #pragma unroll
        for (int q = 0; q < 8; q++) hv[q] = (_Float16)Bs[m * 36 + k0l + q];
        int lane = (m & 15) | (((k0 >> 3) & 3) << 4);
        size_t off = (size_t)i * 16384 + (((size_t)(m >> 4) * 4 + (k0 >> 5)) * 64 + lane) * 8;
        *(f16x8*)(Wf + off) = hv;
    }
}

// ---- L12: out[64j+i] = W_i @ Y_j via MFMA (batch-major stores) ------------
__global__ __launch_bounds__(256) void k_final(const _Float16* __restrict__ Wf,
                                               const _Float16* __restrict__ Yf,
                                               float* __restrict__ out)
{
    int i = blockIdx.x, j = blockIdx.y;
    int tid = threadIdx.x, wave = tid >> 6, lane = tid & 63;
    const _Float16* Ab = Yf + (size_t)j * 8192;
    const _Float16* Bb = Wf + (size_t)i * 16384;
    f32x4 acc[4][2] = {};
    #pragma unroll
    for (int ks = 0; ks < 4; ks++) {
        f16x8 a[4], b[2];
        #pragma unroll
        for (int bt = 0; bt < 4; bt++)
            a[bt] = *(const f16x8*)(Ab + (((size_t)bt * 4 + ks) * 64 + lane) * 8);
        #pragma unroll
        for (int nn = 0; nn < 2; nn++)
            b[nn] = *(const f16x8*)(Bb + (((size_t)(wave * 2 + nn) * 4 + ks) * 64 + lane) * 8);
        #pragma unroll
        for (int bt = 0; bt < 4; bt++)
            #pragma unroll
            for (int nn = 0; nn < 2; nn++)
                acc[bt][nn] = __builtin_amdgcn_mfma_f32_16x16x32_f16(a[bt], b[nn], acc[bt][nn], 0, 0, 0);
    }
    float* slab = out + (size_t)(j * 64 + i) * 8192;
    int nlo = lane & 15, b0 = (lane >> 4) * 4;
    #pragma unroll
    for (int bt = 0; bt < 4; bt++)
        #pragma unroll
        for (int nn = 0; nn < 2; nn++) {
            int n = (wave * 2 + nn) * 16 + nlo;
            __builtin_nontemporal_store(acc[bt][nn],
                (f32x4*)&slab[(size_t)n * 64 + bt * 16 + b0]);
        }
}

static inline void addjob(AJobs& J, int& n, int type, int a, int bt, int c, int aux)
{
    J.a[n] = make_int4(a, bt, c, type);
    J.aux[n] = aux;
    n++;
}

extern "C" void kernel_launch(void* const* d_in, const int* in_sizes, int n_in,
                              void* d_out, int out_size, void* d_ws, size_t ws_size,
                              hipStream_t stream)
{
    const float* t  = (const float*)d_in[0];
    const float* x0 = (const float*)d_in[1];
    const float* S  = (const float*)d_in[2];
    const float* D  = (const float*)d_in[3];
    float* out = (float*)d_out;
    float* ws  = (float*)d_ws;
    _Float16* Wf = (_Float16*)(ws + FWOFFI);
    _Float16* Yf = (_Float16*)(ws + FYOFFI);

    // L1: Xa, XaT, Xa2, Xa2T (+ Y'0, Yf0, Wf0)
    hipLaunchKernelGGL(k_x2, dim3(4), dim3(256), 0, stream, t, x0, S, D, ws);

    AJobs J; int n;
    // L2: Xa3 = Xa2*Xa ; Xa4 = Xa2*Xa2   (emit transposes)
    n = 0;
    addjob(J, n, 0, XOFF(2), XTOFF(1), XOFF(3), XTOFF(3));
    addjob(J, n, 0, XOFF(2), XTOFF(2), XOFF(4), XTOFF(4));
    hipLaunchKernelGGL(k_atom, dim3(n), dim3(256), 0, stream, ws, J);
    // L3: Xa5..Xa8 = Xa4 * Xa1..Xa4
    n = 0;
    for (int q = 1; q <= 4; q++)
        addjob(J, n, 0, XOFF(4), XTOFF(q), XOFF(4 + q), XTOFF(4 + q));
    hipLaunchKernelGGL(k_atom, dim3(n), dim3(256), 0, stream, ws, J);

    // L4/L5: Paterson-Stockmeyer for E^1..E^64
    hipLaunchKernelGGL(k_ps1, dim3(64, 4), dim3(256), 0, stream, ws);
    hipLaunchKernelGGL(k_ps2, dim3(64, 4), dim3(256), 0, stream, ws);

    // L6..L11: G-squarings + Y' doubling (Yf frags emitted inline)
    for (int d = 0; d < 6; d++) {
        n = 0;
        if (d < 5) addjob(J, n, 0, GP(d), GTP(d), GP(d + 1), GTP(d + 1));
        for (int jj = 0; jj < (1 << d); jj++)
            addjob(J, n, 1, YP(jj), GP(d), YP((1 << d) + jj), (1 << d) + jj);
        hipLaunchKernelGGL(k_atom, dim3(n), dim3(256), 0, stream, ws, J);
    }

    // L12: out[64j+i] = W_i @ Y_j
    hipLaunchKernelGGL(k_final, dim3(64, 64), dim3(256), 0, stream, Wf, Yf, out);
}

// Round 12
// 214.429 us; speedup vs baseline: 1.3881x; 1.3881x over previous
//
#include <hip/hip_runtime.h>
#include <math.h>

#define DIM 128
// ws float layout:
//   Xa^q  q=1..8      : XA(q) = (q-1)*16384       (Xa = 16*dt*A)
//   G^(2^s) s=0..5    : GS(s) = (8+s)*16384       (GS(0) = E^64)
//   Y[j] f32 j=0..63  : YF(j) = 14*16384 + j*8192 ([dim][batch])
//   Wf f16 frags      : FW = 46*16384 floats (64 mats x 16384 halves)
//   Yf f16 frags      : FY = 78*16384 floats (64 mats x 8192 halves)
#define XA(q)   (((q) - 1) * 16384)
#define GS(s)   ((8 + (s)) * 16384)
#define YF(j)   (14 * 16384 + (j) * 8192)
#define FW      (46 * 16384)
#define FY      (78 * 16384)
#define ALPHA   16.0f

typedef _Float16 f16x8 __attribute__((ext_vector_type(8)));
typedef float    f32x4 __attribute__((ext_vector_type(4)));

__device__ __forceinline__ float4 ld4(const float* p) { return *(const float4*)p; }

// vectorized transpose-stage: AT[k][d] = A[d][k], AT row stride 132
__device__ __forceinline__ void stageAT(const float* __restrict__ A, float* AT, int tid)
{
    for (int idx = tid * 4; idx < DIM * DIM; idx += 1024) {
        float4 v = ld4(&A[idx]);
        int d = idx >> 7, k = idx & 127;
        AT[(k + 0) * 132 + d] = v.x;
        AT[(k + 1) * 132 + d] = v.y;
        AT[(k + 2) * 132 + d] = v.z;
        AT[(k + 3) * 132 + d] = v.w;
    }
}

__device__ __forceinline__ void mm_core(const float* AT, const float* Bs,
                                        float (&acc)[4][4], int tid)
{
    int d0 = (tid & 31) * 4, c0 = (tid >> 5) * 4;
    #pragma unroll 4
    for (int k = 0; k < DIM; k++) {
        float4 a4 = ld4(&AT[k * 132 + d0]);
        float4 b4 = ld4(&Bs[k * 36 + c0]);
        float a_[4] = {a4.x, a4.y, a4.z, a4.w};
        float b_[4] = {b4.x, b4.y, b4.z, b4.w};
        #pragma unroll
        for (int i = 0; i < 4; i++)
            #pragma unroll
            for (int j = 0; j < 4; j++) acc[i][j] += a_[i] * b_[j];
    }
}

// ---- L1: Xa + Xa^2 panel (4 WGs); side: Y0 f32, Wf0, Yf0 ------------------
__global__ __launch_bounds__(256) void k_x2(const float* __restrict__ t,
                                            const float* __restrict__ x0,
                                            const float* __restrict__ S,
                                            const float* __restrict__ D,
                                            float* __restrict__ ws)
{
    __shared__ __align__(16) float AT[DIM * 132];
    __shared__ __align__(16) float Bs[DIM * 36];
    int tid = threadIdx.x, bid = blockIdx.x, cpan = bid * 32;
    float sc = (t[1] - t[0]) * ALPHA;
    for (int e = tid; e < 16384; e += 256) {
        int r = e >> 7, c = e & 127;
        float a;
        if (r == c)      a = -log1pf(expf(D[r]));
        else if (r < c)  a =  S[(r * (2 * DIM - r - 1)) / 2 + (c - r - 1)];
        else             a = -S[(c * (2 * DIM - c - 1)) / 2 + (r - c - 1)];
        a *= sc;
        AT[c * 132 + r] = a;
        if (c >= cpan && c < cpan + 32) Bs[r * 36 + (c - cpan)] = a;
        if (bid == 0) ws[XA(1) + e] = a;
    }
    if (bid == 1) for (int e = tid; e < 8192; e += 256) ws[YF(0) + e] = x0[e];
    if (bid == 2) {                                  // W0 = I fragment table
        _Float16* Wf = (_Float16*)(ws + FW);
        for (int ch = tid; ch < 2048; ch += 256) {
            int m = ch >> 4, k0 = (ch & 15) << 3;
            f16x8 hv;
            #pragma unroll
            for (int q = 0; q < 8; q++) hv[q] = (m == k0 + q) ? (_Float16)1.0f : (_Float16)0.0f;
            int lane = (m & 15) | (((k0 >> 3) & 3) << 4);
            size_t off = (((size_t)(m >> 4) * 4 + (k0 >> 5)) * 64 + lane) * 8;
            *(f16x8*)(Wf + off) = hv;
        }
    }
    if (bid == 3) {                                  // Y0 fragment table
        _Float16* Yf = (_Float16*)(ws + FY);
        for (int slot = tid; slot < 1024; slot += 256) {
            int ls = slot & 63, tile = slot >> 6;
            int n = (tile >> 2) * 16 + (ls & 15);
            int k0 = (tile & 3) * 32 + ((ls >> 4) & 3) * 8;
            f16x8 hv;
            #pragma unroll
            for (int q = 0; q < 8; q++) hv[q] = (_Float16)x0[(size_t)(k0 + q) * 64 + n];
            *(f16x8*)(Yf + (size_t)slot * 8) = hv;
        }
    }
    __syncthreads();
    float acc[4][4] = {};
    mm_core(AT, Bs, acc, tid);
    int d0 = (tid & 31) * 4, c0 = (tid >> 5) * 4;
    #pragma unroll
    for (int r = 0; r < 4; r++) {
        float4 st = make_float4(acc[r][0], acc[r][1], acc[r][2], acc[r][3]);
        *(float4*)&ws[XA(2) + (size_t)(d0 + r) * DIM + cpan + c0] = st;
    }
}

// ---- generic panel-job matmul (f32), optional inline Yf frag emission -----
// job: {aoff, boff, coff, w = cpan | ncols<<8 | (fragj+1)<<17}
struct Jobs { int4 jb[64]; };

__global__ __launch_bounds__(256) void k_lvl(float* __restrict__ ws, Jobs jobs)
{
    __shared__ __align__(16) float AT[DIM * 132];
    __shared__ __align__(16) float Bs[DIM * 36];
    const int4 jb = jobs.jb[blockIdx.x];
    const int cpan  = jb.w & 127;
    const int ncols = (jb.w >> 8) & 255;
    const int fragj = ((jb.w >> 17) & 127) - 1;
    const float* A = ws + jb.x;
    const float* B = ws + jb.y;
    float* C = ws + jb.z;
    const int tid = threadIdx.x;
    stageAT(A, AT, tid);
    for (int s = tid; s < DIM * 8; s += 256) {
        int k = s >> 3, cc4 = (s & 7) * 4;
        *(float4*)&Bs[k * 36 + cc4] = ld4(&B[(size_t)k * ncols + cpan + cc4]);
    }
    __syncthreads();
    float acc[4][4] = {};
    mm_core(AT, Bs, acc, tid);
    int d0 = (tid & 31) * 4, c0 = (tid >> 5) * 4;
    #pragma unroll
    for (int r = 0; r < 4; r++) {
        float4 st = make_float4(acc[r][0], acc[r][1], acc[r][2], acc[r][3]);
        *(float4*)&C[(size_t)(d0 + r) * ncols + cpan + c0] = st;
    }
    if (fragj < 0) return;
    __syncthreads();
    #pragma unroll
    for (int r = 0; r < 4; r++)
        #pragma unroll
        for (int j = 0; j < 4; j++) Bs[(d0 + r) * 36 + c0 + j] = acc[r][j];
    __syncthreads();
    _Float16* Yf = (_Float16*)(ws + FY) + (size_t)fragj * 8192;
    for (int ch = tid; ch < 512; ch += 256) {
        int nloc = ch >> 4, k0 = (ch & 15) * 8;     // local batch col, dim octet
        f16x8 hv;
        #pragma unroll
        for (int q = 0; q < 8; q++) hv[q] = (_Float16)Bs[(k0 + q) * 36 + nloc];
        int n = cpan + nloc;
        int lane = (n & 15) | (((k0 >> 3) & 3) << 4);
        size_t off = (((size_t)(n >> 4) * 4 + (k0 >> 5)) * 64 + lane) * 8;
        *(f16x8*)(Yf + off) = hv;
    }
}

// ---- L4: degree-15 PS, single stage: E^i = Xa8 @ P1(i) + P0(i) ------------
// i = 1..64 (grid 64x4); i<64 -> Wf frags, i==64 -> G f32.  c_n = (i/16)^n/n!
__global__ __launch_bounds__(256) void k_ps(float* __restrict__ ws)
{
    __shared__ __align__(16) float AT[DIM * 132];
    __shared__ __align__(16) float Bs[DIM * 36];
    int i = blockIdx.x + 1, cpan = blockIdx.y * 32, tid = threadIdx.x;
    float r = (float)i / ALPHA;
    float c[16]; c[0] = 1.0f;
    #pragma unroll
    for (int n = 1; n < 16; n++) c[n] = c[n - 1] * (r / (float)n);
    stageAT(ws + XA(8), AT, tid);
    for (int s = tid; s < DIM * 8; s += 256) {
        int k = s >> 3, cc4 = (s & 7) * 4;
        float4 b = make_float4(0.f, 0.f, 0.f, 0.f);
        #pragma unroll
        for (int q = 1; q < 8; q++) {
            float4 x = ld4(&ws[XA(q) + (size_t)k * DIM + cpan + cc4]);
            b.x += c[8 + q] * x.x; b.y += c[8 + q] * x.y;
            b.z += c[8 + q] * x.z; b.w += c[8 + q] * x.w;
        }
        int col = cpan + cc4;
        if (k >= col && k < col + 4) (&b.x)[k - col] += c[8];
        *(float4*)&Bs[k * 36 + cc4] = b;
    }
    __syncthreads();
    float acc[4][4] = {};
    mm_core(AT, Bs, acc, tid);
    int d0 = (tid & 31) * 4, c0 = (tid >> 5) * 4;
    #pragma unroll
    for (int rr = 0; rr < 4; rr++) {
        int dd = d0 + rr;
        float add[4] = {0.f, 0.f, 0.f, 0.f};
        #pragma unroll
        for (int q = 1; q < 8; q++) {
            float4 x = ld4(&ws[XA(q) + (size_t)dd * DIM + cpan + c0]);
            add[0] += c[q] * x.x; add[1] += c[q] * x.y;
            add[2] += c[q] * x.z; add[3] += c[q] * x.w;
        }
        int col0 = cpan + c0;
        if (dd >= col0 && dd < col0 + 4) add[dd - col0] += 1.0f;
        #pragma unroll
        for (int j = 0; j < 4; j++) acc[rr][j] += add[j];
    }
    if (i == 64) {                                   // G = E^64 f32
        #pragma unroll
        for (int rr = 0; rr < 4; rr++) {
            float4 st = make_float4(acc[rr][0], acc[rr][1], acc[rr][2], acc[rr][3]);
            *(float4*)&ws[GS(0) + (size_t)(d0 + rr) * DIM + cpan + c0] = st;
        }
        return;
    }
    __syncthreads();
    #pragma unroll
    for (int rr = 0; rr < 4; rr++)
        #pragma unroll
        for (int j = 0; j < 4; j++) Bs[(d0 + rr) * 36 + c0 + j] = acc[rr][j];
    __syncthreads();
    _Float16* Wf = (_Float16*)(ws + FW);
    for (int ch = tid; ch < 512; ch += 256) {
        int m = ch >> 2, k0l = (ch & 3) * 8, k0 = cpan + k0l;
        f16x8 hv;
        #pragma unroll
        for (int q = 0; q < 8; q++) hv[q] = (_Float16)Bs[m * 36 + k0l + q];
        int lane = (m & 15) | (((k0 >> 3) & 3) << 4);
        size_t off = (size_t)i * 16384 + (((size_t)(m >> 4) * 4 + (k0 >> 5)) * 64 + lane) * 8;
        *(f16x8*)(Wf + off) = hv;
    }
}

// ---- L11: out[64j+i] = W_i @ Y_j via MFMA (batch-major stores) ------------
__global__ __launch_bounds__(256) void k_final(const _Float16* __restrict__ Wf,
                                               const _Float16* __restrict__ Yf,
                                               float* __restrict__ out)
{
    int i = blockIdx.x, j = blockIdx.y;
    int tid = threadIdx.x, wave = tid >> 6, lane = tid & 63;
    const _Float16* Ab = Yf + (size_t)j * 8192;
    const _Float16* Bb = Wf + (size_t)i * 16384;
    f32x4 acc[4][2] = {};
    #pragma unroll
    for (int ks = 0; ks < 4; ks++) {
        f16x8 a[4], b[2];
        #pragma unroll
        for (int bt = 0; bt < 4; bt++)
            a[bt] = *(const f16x8*)(Ab + (((size_t)bt * 4 + ks) * 64 + lane) * 8);
        #pragma unroll
        for (int nn = 0; nn < 2; nn++)
            b[nn] = *(const f16x8*)(Bb + (((size_t)(wave * 2 + nn) * 4 + ks) * 64 + lane) * 8);
        #pragma unroll
        for (int bt = 0; bt < 4; bt++)
            #pragma unroll
            for (int nn = 0; nn < 2; nn++)
                acc[bt][nn] = __builtin_amdgcn_mfma_f32_16x16x32_f16(a[bt], b[nn], acc[bt][nn], 0, 0, 0);
    }
    float* slab = out + (size_t)(j * 64 + i) * 8192;
    int nlo = lane & 15, b0 = (lane >> 4) * 4;
    #pragma unroll
    for (int bt = 0; bt < 4; bt++)
        #pragma unroll
        for (int nn = 0; nn < 2; nn++) {
            int n = (wave * 2 + nn) * 16 + nlo;
            __builtin_nontemporal_store(acc[bt][nn],
                (f32x4*)&slab[(size_t)n * 64 + bt * 16 + b0]);
        }
}

static inline void addjob(Jobs& J, int& n, int a, int b, int c,
                          int cpan, int ncols, int fragj)
{
    J.jb[n++] = make_int4(a, b, c, cpan | (ncols << 8) | ((fragj + 1) << 17));
}

static inline void addmm(Jobs& J, int& n, int a, int b, int c, int ncols, int fragj)
{
    for (int p = 0; p < ncols; p += 32) addjob(J, n, a, b, c, p, ncols, fragj);
}

extern "C" void kernel_launch(void* const* d_in, const int* in_sizes, int n_in,
                              void* d_out, int out_size, void* d_ws, size_t ws_size,
                              hipStream_t stream)
{
    const float* t  = (const float*)d_in[0];
    const float* x0 = (const float*)d_in[1];
    const float* S  = (const float*)d_in[2];
    const float* D  = (const float*)d_in[3];
    float* out = (float*)d_out;
    float* ws  = (float*)d_ws;
    _Float16* Wf = (_Float16*)(ws + FW);
    _Float16* Yf = (_Float16*)(ws + FY);

    // L1: Xa, Xa^2 (+ Y0 f32, Wf0, Yf0)
    hipLaunchKernelGGL(k_x2, dim3(4), dim3(256), 0, stream, t, x0, S, D, ws);

    Jobs J; int n;
    // L2: Xa3 = Xa2*Xa ; Xa4 = Xa2*Xa2            (8 WGs)
    n = 0;
    addmm(J, n, XA(2), XA(1), XA(3), 128, -1);
    addmm(J, n, XA(2), XA(2), XA(4), 128, -1);
    hipLaunchKernelGGL(k_lvl, dim3(n), dim3(256), 0, stream, ws, J);
    // L3: Xa5..Xa8 = Xa4 * Xa1..Xa4               (16 WGs)
    n = 0;
    for (int q = 1; q <= 4; q++) addmm(J, n, XA(4), XA(q), XA(4 + q), 128, -1);
    hipLaunchKernelGGL(k_lvl, dim3(n), dim3(256), 0, stream, ws, J);

    // L4: degree-15 PS -> W frags (i=1..63) + G = E^64 f32  (256 WGs)
    hipLaunchKernelGGL(k_ps, dim3(64, 4), dim3(256), 0, stream, ws);

    // L5..L10: binary chain; G-squarings + Y fills with inline Yf emission
    n = 0;  // C1: G2 ; Y1
    addmm(J, n, GS(0), GS(0), GS(1), 128, -1);
    addmm(J, n, GS(0), YF(0), YF(1), 64, 1);
    hipLaunchKernelGGL(k_lvl, dim3(n), dim3(256), 0, stream, ws, J);
    n = 0;  // C2: G4 ; Y2,Y3
    addmm(J, n, GS(1), GS(1), GS(2), 128, -1);
    addmm(J, n, GS(1), YF(0), YF(2), 64, 2);
    addmm(J, n, GS(1), YF(1), YF(3), 64, 3);
    hipLaunchKernelGGL(k_lvl, dim3(n), dim3(256), 0, stream, ws, J);
    n = 0;  // C3: G8 ; Y4..7
    addmm(J, n, GS(2), GS(2), GS(3), 128, -1);
    for (int jj = 0; jj < 4; jj++)
        addmm(J, n, GS(2), YF(jj), YF(4 + jj), 64, 4 + jj);
    hipLaunchKernelGGL(k_lvl, dim3(n), dim3(256), 0, stream, ws, J);
    n = 0;  // C4: G16 ; Y8..15
    addmm(J, n, GS(3), GS(3), GS(4), 128, -1);
    for (int jj = 0; jj < 8; jj++)
        addmm(J, n, GS(3), YF(jj), YF(8 + jj), 64, 8 + jj);
    hipLaunchKernelGGL(k_lvl, dim3(n), dim3(256), 0, stream, ws, J);
    n = 0;  // C5: G32 ; Y16..31
    addmm(J, n, GS(4), GS(4), GS(5), 128, -1);
    for (int jj = 0; jj < 16; jj++)
        addmm(J, n, GS(4), YF(jj), YF(16 + jj), 64, 16 + jj);
    hipLaunchKernelGGL(k_lvl, dim3(n), dim3(256), 0, stream, ws, J);
    n = 0;  // C6: Y32..63
    for (int jj = 0; jj < 32; jj++)
        addmm(J, n, GS(5), YF(jj), YF(32 + jj), 64, 32 + jj);
    hipLaunchKernelGGL(k_lvl, dim3(n), dim3(256), 0, stream, ws, J);

    // L11: out[64j+i] = W_i @ Y_j
    hipLaunchKernelGGL(k_final, dim3(64, 64), dim3(256), 0, stream, Wf, Yf, out);
}

// Round 13
// 195.573 us; speedup vs baseline: 1.5219x; 1.0964x over previous
//
#include <hip/hip_runtime.h>
#include <math.h>

#define DIM 128
// ws float layout:
//   Xa^q  q=1..8      : XA(q) = (q-1)*16384       (Xa = 16*dt*A)
//   G^(2^s) s=0..4    : GS(s) = (8+s)*16384       (GS(0) = E^64)
//   Y[j] f32 j=0..15  : YF(j) = 14*16384 + j*8192
//   Wf f16 frags      : FW  = 46*16384 floats (64 mats x 16384 halves)
//   Yf f16 frags      : FY  = 78*16384 floats (16 mats x 8192 halves)
//   G16 hi/lo frags   : FGH = 110*16384, FGL = 111*16384 (16384 halves each)
#define XA(q)   (((q) - 1) * 16384)
#define GS(s)   ((8 + (s)) * 16384)
#define YF(j)   (14 * 16384 + (j) * 8192)
#define FW      (46 * 16384)
#define FY      (78 * 16384)
#define FGH     (110 * 16384)
#define FGL     (111 * 16384)
#define ALPHA   16.0f

typedef _Float16 f16x8 __attribute__((ext_vector_type(8)));
typedef float    f32x4 __attribute__((ext_vector_type(4)));

__device__ __forceinline__ float4 ld4(const float* p) { return *(const float4*)p; }

__device__ __forceinline__ void stageAT(const float* __restrict__ A, float* AT, int tid)
{
    for (int idx = tid * 4; idx < DIM * DIM; idx += 1024) {
        float4 v = ld4(&A[idx]);
        int d = idx >> 7, k = idx & 127;
        AT[(k + 0) * 132 + d] = v.x;
        AT[(k + 1) * 132 + d] = v.y;
        AT[(k + 2) * 132 + d] = v.z;
        AT[(k + 3) * 132 + d] = v.w;
    }
}

__device__ __forceinline__ void mm_core(const float* AT, const float* Bs,
                                        float (&acc)[4][4], int tid)
{
    int d0 = (tid & 31) * 4, c0 = (tid >> 5) * 4;
    #pragma unroll 4
    for (int k = 0; k < DIM; k++) {
        float4 a4 = ld4(&AT[k * 132 + d0]);
        float4 b4 = ld4(&Bs[k * 36 + c0]);
        float a_[4] = {a4.x, a4.y, a4.z, a4.w};
        float b_[4] = {b4.x, b4.y, b4.z, b4.w};
        #pragma unroll
        for (int i = 0; i < 4; i++)
            #pragma unroll
            for (int j = 0; j < 4; j++) acc[i][j] += a_[i] * b_[j];
    }
}

// ---- L1: Xa + Xa^2 panel (4 WGs); side: Y0 f32, Wf0, Yf0 ------------------
__global__ __launch_bounds__(256) void k_x2(const float* __restrict__ t,
                                            const float* __restrict__ x0,
                                            const float* __restrict__ S,
                                            const float* __restrict__ D,
                                            float* __restrict__ ws)
{
    __shared__ __align__(16) float AT[DIM * 132];
    __shared__ __align__(16) float Bs[DIM * 36];
    int tid = threadIdx.x, bid = blockIdx.x, cpan = bid * 32;
    float sc = (t[1] - t[0]) * ALPHA;
    for (int e = tid; e < 16384; e += 256) {
        int r = e >> 7, c = e & 127;
        float a;
        if (r == c)      a = -log1pf(expf(D[r]));
        else if (r < c)  a =  S[(r * (2 * DIM - r - 1)) / 2 + (c - r - 1)];
        else             a = -S[(c * (2 * DIM - c - 1)) / 2 + (r - c - 1)];
        a *= sc;
        AT[c * 132 + r] = a;
        if (c >= cpan && c < cpan + 32) Bs[r * 36 + (c - cpan)] = a;
        if (bid == 0) ws[XA(1) + e] = a;
    }
    if (bid == 1) for (int e = tid; e < 8192; e += 256) ws[YF(0) + e] = x0[e];
    if (bid == 2) {                                  // W0 = I fragment table
        _Float16* Wf = (_Float16*)(ws + FW);
        for (int ch = tid; ch < 2048; ch += 256) {
            int m = ch >> 4, k0 = (ch & 15) << 3;
            f16x8 hv;
            #pragma unroll
            for (int q = 0; q < 8; q++) hv[q] = (m == k0 + q) ? (_Float16)1.0f : (_Float16)0.0f;
            int lane = (m & 15) | (((k0 >> 3) & 3) << 4);
            size_t off = (((size_t)(m >> 4) * 4 + (k0 >> 5)) * 64 + lane) * 8;
            *(f16x8*)(Wf + off) = hv;
        }
    }
    if (bid == 3) {                                  // Y0 fragment table
        _Float16* Yf = (_Float16*)(ws + FY);
        for (int slot = tid; slot < 1024; slot += 256) {
            int ls = slot & 63, tile = slot >> 6;
            int n = (tile >> 2) * 16 + (ls & 15);
            int k0 = (tile & 3) * 32 + ((ls >> 4) & 3) * 8;
            f16x8 hv;
            #pragma unroll
            for (int q = 0; q < 8; q++) hv[q] = (_Float16)x0[(size_t)(k0 + q) * 64 + n];
            *(f16x8*)(Yf + (size_t)slot * 8) = hv;
        }
    }
    __syncthreads();
    float acc[4][4] = {};
    mm_core(AT, Bs, acc, tid);
    int d0 = (tid & 31) * 4, c0 = (tid >> 5) * 4;
    #pragma unroll
    for (int r = 0; r < 4; r++) {
        float4 st = make_float4(acc[r][0], acc[r][1], acc[r][2], acc[r][3]);
        *(float4*)&ws[XA(2) + (size_t)(d0 + r) * DIM + cpan + c0] = st;
    }
}

// ---- generic panel-job matmul (f32); optional Yf emission / G16 emission --
// job: {aoff, boff, coff, w = cpan | ncols<<8 | (fragj+1)<<17 | gmode<<25}
struct Jobs { int4 jb[24]; };

__global__ __launch_bounds__(256) void k_lvl(float* __restrict__ ws, Jobs jobs)
{
    __shared__ __align__(16) float AT[DIM * 132];
    __shared__ __align__(16) float Bs[DIM * 36];
    const int4 jb = jobs.jb[blockIdx.x];
    const int cpan  = jb.w & 127;
    const int ncols = (jb.w >> 8) & 255;
    const int fragj = ((jb.w >> 17) & 127) - 1;
    const int gmode = (jb.w >> 25) & 1;
    const float* A = ws + jb.x;
    const float* B = ws + jb.y;
    float* C = ws + jb.z;
    const int tid = threadIdx.x;
    stageAT(A, AT, tid);
    for (int s = tid; s < DIM * 8; s += 256) {
        int k = s >> 3, cc4 = (s & 7) * 4;
        *(float4*)&Bs[k * 36 + cc4] = ld4(&B[(size_t)k * ncols + cpan + cc4]);
    }
    __syncthreads();
    float acc[4][4] = {};
    mm_core(AT, Bs, acc, tid);
    int d0 = (tid & 31) * 4, c0 = (tid >> 5) * 4;
    #pragma unroll
    for (int r = 0; r < 4; r++) {
        float4 st = make_float4(acc[r][0], acc[r][1], acc[r][2], acc[r][3]);
        *(float4*)&C[(size_t)(d0 + r) * ncols + cpan + c0] = st;
    }
    if (fragj < 0 && !gmode) return;
    __syncthreads();
    #pragma unroll
    for (int r = 0; r < 4; r++)
        #pragma unroll
        for (int j = 0; j < 4; j++) Bs[(d0 + r) * 36 + c0 + j] = acc[r][j];
    __syncthreads();
    if (fragj >= 0) {                                // Yf emission (ncols=64)
        _Float16* Yf = (_Float16*)(ws + FY) + (size_t)fragj * 8192;
        for (int ch = tid; ch < 512; ch += 256) {
            int nloc = ch >> 4, k0 = (ch & 15) * 8;
            f16x8 hv;
            #pragma unroll
            for (int q = 0; q < 8; q++) hv[q] = (_Float16)Bs[(k0 + q) * 36 + nloc];
            int n = cpan + nloc;
            int lane = (n & 15) | (((k0 >> 3) & 3) << 4);
            size_t off = (((size_t)(n >> 4) * 4 + (k0 >> 5)) * 64 + lane) * 8;
            *(f16x8*)(Yf + off) = hv;
        }
    } else {                                         // G16 hi/lo emission (ncols=128)
        _Float16* Gh = (_Float16*)(ws + FGH);
        _Float16* Gl = (_Float16*)(ws + FGL);
        for (int ch = tid; ch < 512; ch += 256) {
            int m = ch >> 2, k0l = (ch & 3) * 8, k0 = cpan + k0l;
            f16x8 hv, lv;
            #pragma unroll
            for (int q = 0; q < 8; q++) {
                float v = Bs[m * 36 + k0l + q];
                _Float16 h = (_Float16)v;
                hv[q] = h; lv[q] = (_Float16)(v - (float)h);
            }
            int lane = (m & 15) | (((k0 >> 3) & 3) << 4);
            size_t off = (((size_t)(m >> 4) * 4 + (k0 >> 5)) * 64 + lane) * 8;
            *(f16x8*)(Gh + off) = hv;
            *(f16x8*)(Gl + off) = lv;
        }
    }
}

// ---- L4: degree-15 PS: E^i = Xa8 @ P1(i) + P0(i), i=1..64 -----------------
__global__ __launch_bounds__(256) void k_ps(float* __restrict__ ws)
{
    __shared__ __align__(16) float AT[DIM * 132];
    __shared__ __align__(16) float Bs[DIM * 36];
    int i = blockIdx.x + 1, cpan = blockIdx.y * 32, tid = threadIdx.x;
    float r = (float)i / ALPHA;
    float c[16]; c[0] = 1.0f;
    #pragma unroll
    for (int n = 1; n < 16; n++) c[n] = c[n - 1] * (r / (float)n);
    stageAT(ws + XA(8), AT, tid);
    for (int s = tid; s < DIM * 8; s += 256) {
        int k = s >> 3, cc4 = (s & 7) * 4;
        float4 b = make_float4(0.f, 0.f, 0.f, 0.f);
        #pragma unroll
        for (int q = 1; q < 8; q++) {
            float4 x = ld4(&ws[XA(q) + (size_t)k * DIM + cpan + cc4]);
            b.x += c[8 + q] * x.x; b.y += c[8 + q] * x.y;
            b.z += c[8 + q] * x.z; b.w += c[8 + q] * x.w;
        }
        int col = cpan + cc4;
        if (k >= col && k < col + 4) (&b.x)[k - col] += c[8];
        *(float4*)&Bs[k * 36 + cc4] = b;
    }
    __syncthreads();
    float acc[4][4] = {};
    mm_core(AT, Bs, acc, tid);
    int d0 = (tid & 31) * 4, c0 = (tid >> 5) * 4;
    #pragma unroll
    for (int rr = 0; rr < 4; rr++) {
        int dd = d0 + rr;
        float add[4] = {0.f, 0.f, 0.f, 0.f};
        #pragma unroll
        for (int q = 1; q < 8; q++) {
            float4 x = ld4(&ws[XA(q) + (size_t)dd * DIM + cpan + c0]);
            add[0] += c[q] * x.x; add[1] += c[q] * x.y;
            add[2] += c[q] * x.z; add[3] += c[q] * x.w;
        }
        int col0 = cpan + c0;
        if (dd >= col0 && dd < col0 + 4) add[dd - col0] += 1.0f;
        #pragma unroll
        for (int j = 0; j < 4; j++) acc[rr][j] += add[j];
    }
    if (i == 64) {                                   // G = E^64 f32
        #pragma unroll
        for (int rr = 0; rr < 4; rr++) {
            float4 st = make_float4(acc[rr][0], acc[rr][1], acc[rr][2], acc[rr][3]);
            *(float4*)&ws[GS(0) + (size_t)(d0 + rr) * DIM + cpan + c0] = st;
        }
        return;
    }
    __syncthreads();
    #pragma unroll
    for (int rr = 0; rr < 4; rr++)
        #pragma unroll
        for (int j = 0; j < 4; j++) Bs[(d0 + rr) * 36 + c0 + j] = acc[rr][j];
    __syncthreads();
    _Float16* Wf = (_Float16*)(ws + FW);
    for (int ch = tid; ch < 512; ch += 256) {
        int m = ch >> 2, k0l = (ch & 3) * 8, k0 = cpan + k0l;
        f16x8 hv;
        #pragma unroll
        for (int q = 0; q < 8; q++) hv[q] = (_Float16)Bs[m * 36 + k0l + q];
        int lane = (m & 15) | (((k0 >> 3) & 3) << 4);
        size_t off = (size_t)i * 16384 + (((size_t)(m >> 4) * 4 + (k0 >> 5)) * 64 + lane) * 8;
        *(f16x8*)(Wf + off) = hv;
    }
}

// ---- L9: out[64j+i] = W_i @ Y_j. j>=16: Y_j built in-kernel via G16 passes -
__global__ __launch_bounds__(256) void k_final(const float* __restrict__ ws,
                                               float* __restrict__ out)
{
    __shared__ _Float16 Yl[64 * 136];
    int i = blockIdx.x, j = blockIdx.y;
    int tid = threadIdx.x, wave = tid >> 6, lane = tid & 63;
    const _Float16* Wf = (const _Float16*)(ws + FW);
    const _Float16* Yf = (const _Float16*)(ws + FY);
    const _Float16* Gh = (const _Float16*)(ws + FGH);
    const _Float16* Gl = (const _Float16*)(ws + FGL);
    const int passes = j >> 4;                 // 0..3
    const int base = j & 15;

    f16x8 ya[4][4];
    #pragma unroll
    for (int bt = 0; bt < 4; bt++)
        #pragma unroll
        for (int ks = 0; ks < 4; ks++)
            ya[bt][ks] = *(const f16x8*)(Yf + (size_t)base * 8192 +
                                         ((size_t)(bt * 4 + ks) * 64 + lane) * 8);

    for (int p = 0; p < passes; p++) {         // Y <- G16 * Y (hi/lo B)
        f32x4 pa[4][2] = {};
        #pragma unroll
        for (int ks = 0; ks < 4; ks++) {
            f16x8 gh[2], gl[2];
            #pragma unroll
            for (int nn = 0; nn < 2; nn++) {
                size_t go = (((size_t)(wave * 2 + nn) * 4 + ks) * 64 + lane) * 8;
                gh[nn] = *(const f16x8*)(Gh + go);
                gl[nn] = *(const f16x8*)(Gl + go);
            }
            #pragma unroll
            for (int bt = 0; bt < 4; bt++)
                #pragma unroll
                for (int nn = 0; nn < 2; nn++) {
                    pa[bt][nn] = __builtin_amdgcn_mfma_f32_16x16x32_f16(ya[bt][ks], gh[nn], pa[bt][nn], 0, 0, 0);
                    pa[bt][nn] = __builtin_amdgcn_mfma_f32_16x16x32_f16(ya[bt][ks], gl[nn], pa[bt][nn], 0, 0, 0);
                }
        }
        __syncthreads();
        #pragma unroll
        for (int bt = 0; bt < 4; bt++)
            #pragma unroll
            for (int nn = 0; nn < 2; nn++) {
                int kout = (wave * 2 + nn) * 16 + (lane & 15);
                int b0 = bt * 16 + (lane >> 4) * 4;
                #pragma unroll
                for (int q = 0; q < 4; q++)
                    Yl[(b0 + q) * 136 + kout] = (_Float16)pa[bt][nn][q];
            }
        __syncthreads();
        #pragma unroll
        for (int bt = 0; bt < 4; bt++)
            #pragma unroll
            for (int ks = 0; ks < 4; ks++)
                ya[bt][ks] = *(const f16x8*)&Yl[(bt * 16 + (lane & 15)) * 136 +
                                                ks * 32 + ((lane >> 4) & 3) * 8];
    }

    const _Float16* Bb = Wf + (size_t)i * 16384;
    f32x4 acc[4][2] = {};
    #pragma unroll
    for (int ks = 0; ks < 4; ks++) {
        f16x8 b0v = *(const f16x8*)(Bb + (((size_t)(wave * 2 + 0) * 4 + ks) * 64 + lane) * 8);
        f16x8 b1v = *(const f16x8*)(Bb + (((size_t)(wave * 2 + 1) * 4 + ks) * 64 + lane) * 8);
        #pragma unroll
        for (int bt = 0; bt < 4; bt++) {
            acc[bt][0] = __builtin_amdgcn_mfma_f32_16x16x32_f16(ya[bt][ks], b0v, acc[bt][0], 0, 0, 0);
            acc[bt][1] = __builtin_amdgcn_mfma_f32_16x16x32_f16(ya[bt][ks], b1v, acc[bt][1], 0, 0, 0);
        }
    }
    float* slab = out + (size_t)(j * 64 + i) * 8192;
    int nlo = lane & 15, b0r = (lane >> 4) * 4;
    #pragma unroll
    for (int bt = 0; bt < 4; bt++)
        #pragma unroll
        for (int nn = 0; nn < 2; nn++) {
            int n = (wave * 2 + nn) * 16 + nlo;
            __builtin_nontemporal_store(acc[bt][nn],
                (f32x4*)&slab[(size_t)n * 64 + bt * 16 + b0r]);
        }
}

static inline void addjob(Jobs& J, int& n, int a, int b, int c,
                          int cpan, int ncols, int fragj, int gmode)
{
    J.jb[n++] = make_int4(a, b, c, cpan | (ncols << 8) | ((fragj + 1) << 17) | (gmode << 25));
}

static inline void addmm(Jobs& J, int& n, int a, int b, int c, int ncols,
                         int fragj, int gmode = 0)
{
    for (int p = 0; p < ncols; p += 32) addjob(J, n, a, b, c, p, ncols, fragj, gmode);
}

extern "C" void kernel_launch(void* const* d_in, const int* in_sizes, int n_in,
                              void* d_out, int out_size, void* d_ws, size_t ws_size,
                              hipStream_t stream)
{
    const float* t  = (const float*)d_in[0];
    const float* x0 = (const float*)d_in[1];
    const float* S  = (const float*)d_in[2];
    const float* D  = (const float*)d_in[3];
    float* out = (float*)d_out;
    float* ws  = (float*)d_ws;

    // L1: Xa, Xa^2 (+ Y0 f32, Wf0, Yf0)
    hipLaunchKernelGGL(k_x2, dim3(4), dim3(256), 0, stream, t, x0, S, D, ws);

    Jobs J; int n;
    // L2: Xa3, Xa4
    n = 0;
    addmm(J, n, XA(2), XA(1), XA(3), 128, -1);
    addmm(J, n, XA(2), XA(2), XA(4), 128, -1);
    hipLaunchKernelGGL(k_lvl, dim3(n), dim3(256), 0, stream, ws, J);
    // L3: Xa5..Xa8
    n = 0;
    for (int q = 1; q <= 4; q++) addmm(J, n, XA(4), XA(q), XA(4 + q), 128, -1);
    hipLaunchKernelGGL(k_lvl, dim3(n), dim3(256), 0, stream, ws, J);

    // L4: PS -> Wf (i=1..63) + G = E^64 f32
    hipLaunchKernelGGL(k_ps, dim3(64, 4), dim3(256), 0, stream, ws);

    // L5..L8: chain to Y0..15 (f32 + frags); G16 emitted hi/lo in L8
    n = 0;  // C1: G2 ; Y1
    addmm(J, n, GS(0), GS(0), GS(1), 128, -1);
    addmm(J, n, GS(0), YF(0), YF(1), 64, 1);
    hipLaunchKernelGGL(k_lvl, dim3(n), dim3(256), 0, stream, ws, J);
    n = 0;  // C2: G4 ; Y2,Y3
    addmm(J, n, GS(1), GS(1), GS(2), 128, -1);
    addmm(J, n, GS(1), YF(0), YF(2), 64, 2);
    addmm(J, n, GS(1), YF(1), YF(3), 64, 3);
    hipLaunchKernelGGL(k_lvl, dim3(n), dim3(256), 0, stream, ws, J);
    n = 0;  // C3: G8 ; Y4..7
    addmm(J, n, GS(2), GS(2), GS(3), 128, -1);
    for (int jj = 0; jj < 4; jj++)
        addmm(J, n, GS(2), YF(jj), YF(4 + jj), 64, 4 + jj);
    hipLaunchKernelGGL(k_lvl, dim3(n), dim3(256), 0, stream, ws, J);
    n = 0;  // C4: G16 (f32 + hi/lo frag tables) ; Y8..15
    addmm(J, n, GS(3), GS(3), GS(4), 128, -1, 1);
    for (int jj = 0; jj < 8; jj++)
        addmm(J, n, GS(3), YF(jj), YF(8 + jj), 64, 8 + jj);
    hipLaunchKernelGGL(k_lvl, dim3(n), dim3(256), 0, stream, ws, J);

    // L9: final; j>=16 applies 1..3 G16 MFMA passes in-kernel
    hipLaunchKernelGGL(k_final, dim3(64, 64), dim3(256), 0, stream, ws, out);
}